// Round 8
// baseline (100.543 us; speedup 1.0000x reference)
//
#include <hip/hip_runtime.h>
#include <math.h>

#define NCLASS 100
#define NSEG 30
#define HBINS (NSEG * NCLASS)    // 3000
#define NREP 8                   // fallback path replicas
#define F4_PER_ROW 25            // 100 floats = 25 float4, row-aligned
#define ROWS_PER_GRP 16
#define F4_PER_GRP (F4_PER_ROW * ROWS_PER_GRP)   // 400
#define CE_BLOCKS 1024           // rows/block = 2^20/1024 = 1024 < 65535 -> u16 safe

__device__ __forceinline__ float e4(float4 v) {
    return __expf(v.x) + __expf(v.y) + __expf(v.z) + __expf(v.w);
}

// ---------------------------------------------------------------------------
// Kernel 1: fused CE partial sum + per-segment label histogram.
// Streaming structure of round 4/7 (best). Tail flush:
//  priv=1: block-private ushort replica, plain packed stores (no atomics,
//          no pre-zeroing needed: all 1500 words overwritten every call),
//          per-block loss slot.
//  priv=0: round-7 NREP-8 atomic flush (requires memset'd counts + loss).
// ---------------------------------------------------------------------------
__global__ __launch_bounds__(256) void ce_hist_kernel(
    const float* __restrict__ logits,   // [N, 100]
    const int*   __restrict__ target,   // [N]
    const int*   __restrict__ seg,      // [N]
    int N,
    void*   __restrict__ flush_dst,     // priv: u16[CE_BLOCKS][HBINS] ; else int[NREP][HBINS]
    double* __restrict__ loss_dst,      // priv: double[CE_BLOCKS] ; else double[1]
    int priv)
{
    __shared__ int    lds_hist[HBINS];           // 12 KB
    __shared__ float  part[4][F4_PER_GRP];       // 6.4 KB (per-wave slices)
    __shared__ double lds_loss[4];

    for (int i = threadIdx.x; i < HBINS; i += blockDim.x) lds_hist[i] = 0;
    __syncthreads();

    const int lane          = threadIdx.x & 63;
    const int wv            = threadIdx.x >> 6;
    const int sub           = lane & 3;     // quad sub-index (pass 2)
    const int q             = lane >> 2;    // row within group (pass 2)
    const int wavesPerBlock = blockDim.x >> 6;
    const int gwave         = blockIdx.x * wavesPerBlock + wv;
    const int totWaves      = gridDim.x * wavesPerBlock;
    const int ngroups       = N >> 4;       // N % 16 == 0

    double acc = 0.0;

    for (int grp = gwave; grp < ngroups; grp += totWaves) {
        const int row = grp * ROWS_PER_GRP + q;

        const int t = target[row];
        const int s = seg[row];

        // ---- pass 1: sequential 1024B-coalesced loads + exp partials ----
        const float4* g4 = (const float4*)logits + (size_t)grp * F4_PER_GRP;
        float4 f0 = g4[lane        ];
        float4 f1 = g4[lane + 64   ];
        float4 f2 = g4[lane + 128  ];
        float4 f3 = g4[lane + 192  ];
        float4 f4v= g4[lane + 256  ];
        float4 f5 = g4[lane + 320  ];

        part[wv][lane      ] = e4(f0);
        part[wv][lane + 64 ] = e4(f1);
        part[wv][lane + 128] = e4(f2);
        part[wv][lane + 192] = e4(f3);
        part[wv][lane + 256] = e4(f4v);
        part[wv][lane + 320] = e4(f5);
        if (lane < 16) {
            float4 f6 = g4[lane + 384];
            part[wv][lane + 384] = e4(f6);
        }
        // same-wave producer->consumer: lgkmcnt ordering, no barrier needed

        // ---- pass 2: quad-per-row gather of 25 partials ----
        const int base = F4_PER_ROW * q + sub;
        float e = part[wv][base     ] + part[wv][base + 4 ] + part[wv][base + 8 ]
                + part[wv][base + 12] + part[wv][base + 16] + part[wv][base + 20];
        if (sub == 0) e += part[wv][F4_PER_ROW * q + 24];
        e += __shfl_xor(e, 1);
        e += __shfl_xor(e, 2);

        // x[target]: L1/L2-hot gather (this CU just streamed those lines)
        const float xt = logits[(size_t)row * NCLASS + t];

        if (sub == 0) {
            acc += (double)(__logf(e) - xt);
            atomicAdd(&lds_hist[s * NCLASS + t], 1);
        }
    }

    // full-wave sum of acc (nonzero only on sub==0 lanes)
    #pragma unroll
    for (int off = 32; off; off >>= 1) acc += __shfl_xor(acc, off);
    if (lane == 0) lds_loss[wv] = acc;
    __syncthreads();                 // also fences LDS hist atomics

    if (priv) {
        if (threadIdx.x == 0) {
            double b = 0.0;
            for (int w = 0; w < wavesPerBlock; ++w) b += lds_loss[w];
            loss_dst[blockIdx.x] = b;
        }
        // packed u16 store of the whole histogram (full overwrite, no atomics)
        unsigned int* my = (unsigned int*)flush_dst + (size_t)blockIdx.x * (HBINS / 2);
        for (int i = threadIdx.x; i < HBINS / 2; i += blockDim.x) {
            unsigned int u = (unsigned int)lds_hist[2 * i]
                           | ((unsigned int)lds_hist[2 * i + 1] << 16);
            my[i] = u;
        }
    } else {
        if (threadIdx.x == 0) {
            double b = 0.0;
            for (int w = 0; w < wavesPerBlock; ++w) b += lds_loss[w];
            atomicAdd(loss_dst, b);
        }
        int* my = (int*)flush_dst + (size_t)(blockIdx.x & (NREP - 1)) * HBINS;
        for (int i = threadIdx.x; i < HBINS; i += blockDim.x) {
            int c = lds_hist[i];
            if (c) atomicAdd(&my[i], c);
        }
    }
}

// ---------------------------------------------------------------------------
// Kernel 2a (priv path): grid = NSEG+1 blocks.
// Blocks 0..29: sum u16 replicas for segment b (coalesced: 100 contiguous
// ushorts per replica row), then first-max argmax (jnp tie rule).
// Block 30: reduce per-block loss partials, write out[0].
// ---------------------------------------------------------------------------
__global__ __launch_bounds__(256) void finalize_priv_kernel(
    const unsigned short* __restrict__ counts,   // [CE_BLOCKS][HBINS]
    const double* __restrict__ loss_part,        // [CE_BLOCKS]
    int N,
    int* __restrict__ g_mode,
    float* __restrict__ out_loss)
{
    __shared__ int    tot2[2][NCLASS];
    __shared__ double ls[4];

    const int b = blockIdx.x;
    if (b < NSEG) {
        const int c    = threadIdx.x & 127;
        const int half = threadIdx.x >> 7;           // 0 or 1
        int v = 0;
        if (c < NCLASS) {
            const unsigned short* base =
                counts + (size_t)half * (CE_BLOCKS / 2) * HBINS + b * NCLASS + c;
            for (int r = 0; r < CE_BLOCKS / 2; ++r)
                v += base[(size_t)r * HBINS];
            tot2[half][c] = v;
        }
        __syncthreads();
        if (threadIdx.x < 64) {
            int bestKey = -1;
            for (int c2 = threadIdx.x; c2 < NCLASS; c2 += 64) {
                int key = ((tot2[0][c2] + tot2[1][c2]) << 7) | (127 - c2);
                bestKey = max(bestKey, key);
            }
            #pragma unroll
            for (int off = 32; off; off >>= 1)
                bestKey = max(bestKey, __shfl_xor(bestKey, off));
            if (threadIdx.x == 0) g_mode[b] = 127 - (bestKey & 127);
        }
    } else {
        double v = 0.0;
        for (int i = threadIdx.x; i < CE_BLOCKS; i += blockDim.x) v += loss_part[i];
        #pragma unroll
        for (int off = 32; off; off >>= 1) v += __shfl_xor(v, off);
        if ((threadIdx.x & 63) == 0) ls[threadIdx.x >> 6] = v;
        __syncthreads();
        if (threadIdx.x == 0)
            out_loss[0] = (float)((ls[0] + ls[1] + ls[2] + ls[3]) / (double)N);
    }
}

// ---------------------------------------------------------------------------
// Kernel 2b (fallback path): round-7 single-block finalize over NREP replicas.
// ---------------------------------------------------------------------------
__global__ void finalize_fallback_kernel(
    const int* __restrict__ g_counts,
    const double* __restrict__ g_loss,
    int N,
    int* __restrict__ g_mode,
    float* __restrict__ out_loss)
{
    const int t = threadIdx.x;        // 256 threads
    const int s = t >> 3;             // segment
    const int j = t & 7;
    if (s < NSEG) {
        int bestKey = -1;
        for (int c = j; c < NCLASS; c += 8) {
            int v = 0;
            #pragma unroll
            for (int r = 0; r < NREP; ++r)
                v += g_counts[r * HBINS + s * NCLASS + c];
            int key = (v << 7) | (127 - c);
            bestKey = max(bestKey, key);
        }
        bestKey = max(bestKey, __shfl_xor(bestKey, 1));
        bestKey = max(bestKey, __shfl_xor(bestKey, 2));
        bestKey = max(bestKey, __shfl_xor(bestKey, 4));
        if (j == 0) g_mode[s] = 127 - (bestKey & 127);
    }
    if (t == 0) out_loss[0] = (float)(g_loss[0] / (double)N);
}

// ---------------------------------------------------------------------------
// Kernel 3: relabeled[i] = mode[seg[i]] written as fp32
// ---------------------------------------------------------------------------
__global__ __launch_bounds__(256) void relabel_kernel(
    const int* __restrict__ seg,
    const int* __restrict__ g_mode,
    float* __restrict__ out,
    int N)
{
    __shared__ float mode_f[NSEG];
    for (int i = threadIdx.x; i < NSEG; i += blockDim.x)
        mode_f[i] = (float)g_mode[i];
    __syncthreads();

    int idx    = blockIdx.x * blockDim.x + threadIdx.x;
    int stride = gridDim.x * blockDim.x;
    for (int i = idx; i < N; i += stride)
        out[i] = mode_f[seg[i]];
}

// ---------------------------------------------------------------------------
extern "C" void kernel_launch(void* const* d_in, const int* in_sizes, int n_in,
                              void* d_out, int out_size, void* d_ws, size_t ws_size,
                              hipStream_t stream)
{
    const float* logits = (const float*)d_in[0];
    const int*   target = (const int*)d_in[1];
    const int*   seg    = (const int*)d_in[2];
    float* out = (float*)d_out;

    const int N = in_sizes[1];          // N_PIXELS (2^20, divisible by 16)

    const size_t loss_bytes   = (size_t)CE_BLOCKS * sizeof(double);          // 8 KB
    const size_t counts_bytes = (size_t)CE_BLOCKS * HBINS * sizeof(unsigned short); // 6.0 MB
    const size_t need_priv    = loss_bytes + counts_bytes + 256;

    if (ws_size >= need_priv) {
        // atomic-free path: no memset needed (every ws word we read is
        // overwritten by ce_hist/finalize on every call)
        double*         loss_part = (double*)d_ws;
        unsigned short* counts    = (unsigned short*)((char*)d_ws + loss_bytes);
        int*            g_mode    = (int*)((char*)d_ws + loss_bytes + counts_bytes);

        ce_hist_kernel<<<CE_BLOCKS, 256, 0, stream>>>(
            logits, target, seg, N, (void*)counts, loss_part, 1);
        finalize_priv_kernel<<<NSEG + 1, 256, 0, stream>>>(
            counts, loss_part, N, g_mode, out);
        relabel_kernel<<<2048, 256, 0, stream>>>(seg, g_mode, out + 1, N);
    } else {
        // round-7 fallback: memset + NREP-8 atomic flush
        double* g_loss   = (double*)d_ws;
        int*    g_counts = (int*)((char*)d_ws + 16);
        int*    g_mode   = (int*)((char*)d_ws + 16 + (size_t)NREP * HBINS * sizeof(int));

        hipMemsetAsync(d_ws, 0, 16 + (size_t)NREP * HBINS * sizeof(int), stream);
        ce_hist_kernel<<<CE_BLOCKS, 256, 0, stream>>>(
            logits, target, seg, N, (void*)g_counts, g_loss, 0);
        finalize_fallback_kernel<<<1, 256, 0, stream>>>(
            g_counts, g_loss, N, g_mode, out);
        relabel_kernel<<<2048, 256, 0, stream>>>(seg, g_mode, out + 1, N);
    }
}